// Round 3
// baseline (10145.989 us; speedup 1.0000x reference)
//
#include <hip/hip_runtime.h>
#include <math.h>

// ---------------------------------------------------------------------------
// AE_control: B=1024, T=512, D=64, K=9, NUM_M=64, NUM_N=32, SCALE=1
// Outputs (flat f32): s_hat[512K], n_hat[512K], idx_s[512K], idx_n[512K]
// idx needs exact argmin vs an f64 reference -> encoder + d2/argmin in f64.
// Decoder + FC stay f32 (2% tanh tolerance).
// ---------------------------------------------------------------------------

#define TB 512
#define BATCH 1024

// (nmat, C, C, 9) f32 -> (nmat, 9, C, C) f64  [k][cin][cout]
__global__ __launch_bounds__(256) void transpose_w_f64_kernel(
    const float* __restrict__ w, double* __restrict__ wT, int C, int nmat) {
  int total = nmat * C * C * 9;
  for (int i = blockIdx.x * blockDim.x + threadIdx.x; i < total;
       i += gridDim.x * blockDim.x) {
    int mat = i / (C * C * 9);
    int r = i % (C * C * 9);
    int cout = r / (C * 9);
    int rem = r % (C * 9);
    int cin = rem / 9;
    int k = rem % 9;
    wT[mat * C * C * 9 + (k * C + cin) * C + cout] = (double)w[i];
  }
}

// (nmat, C, C, 9) f32 -> (nmat, 9, C, C) f32
__global__ __launch_bounds__(256) void transpose_w_f32_kernel(
    const float* __restrict__ w, float* __restrict__ wT, int C, int nmat) {
  int total = nmat * C * C * 9;
  for (int i = blockIdx.x * blockDim.x + threadIdx.x; i < total;
       i += gridDim.x * blockDim.x) {
    int mat = i / (C * C * 9);
    int r = i % (C * C * 9);
    int cout = r / (C * 9);
    int rem = r % (C * 9);
    int cin = rem / 9;
    int k = rem % 9;
    wT[mat * C * C * 9 + (k * C + cin) * C + cout] = w[i];
  }
}

// enc0 fused block (f64): x f32 (BC,512) -> out f64 (BC,64,512)
__global__ __launch_bounds__(256) void enc0_f64_kernel(
    const float* __restrict__ x, const float* __restrict__ w1,
    const float* __restrict__ b1, const double* __restrict__ w2T,
    const float* __restrict__ b2, const float* __restrict__ wsc,
    const float* __restrict__ bsc, double* __restrict__ out) {
  __shared__ double xs[80];
  __shared__ double w1s[576];
  __shared__ double b1s[64];
  __shared__ double mid[64 * 72];
  int b = blockIdx.y;
  int t0 = blockIdx.x * 64;
  int tid = threadIdx.x;
  if (tid < 80) {
    int t = t0 - 8 + tid;
    xs[tid] = (t >= 0 && t < TB) ? (double)x[b * TB + t] : 0.0;
  }
  for (int i = tid; i < 576; i += 256) w1s[i] = (double)w1[i];
  if (tid < 64) b1s[tid] = (double)b1[tid];
  __syncthreads();
  // mid[cout][tt], tt in [0,72): t = t0-4+tt ; zero outside [0,TB) (SAME pad)
  for (int e = tid; e < 64 * 72; e += 256) {
    int cout = e / 72, tt = e % 72;
    int t = t0 - 4 + tt;
    double acc = b1s[cout];
#pragma unroll
    for (int k = 0; k < 9; ++k) acc = fma(w1s[cout * 9 + k], xs[tt + k], acc);
    mid[e] = (t >= 0 && t < TB) ? fmax(acc, 0.0) : 0.0;
  }
  __syncthreads();
  int wave = __builtin_amdgcn_readfirstlane(tid >> 6);
  int lane = tid & 63;
  int cbase = wave * 16;
  double acc[16];
#pragma unroll
  for (int j = 0; j < 16; ++j) acc[j] = (double)b2[cbase + j];
  for (int cin = 0; cin < 64; ++cin) {
#pragma unroll
    for (int k = 0; k < 9; ++k) {
      double xv = mid[cin * 72 + lane + k];
      const double* wp = w2T + (k * 64 + cin) * 64 + cbase;
#pragma unroll
      for (int j = 0; j < 16; ++j) acc[j] = fma(xv, wp[j], acc[j]);
    }
  }
  double xc = xs[8 + lane];
#pragma unroll
  for (int j = 0; j < 16; ++j) {
    double v = acc[j] + fma((double)wsc[cbase + j], xc, (double)bsc[cbase + j]);
    out[(b * 64 + cbase + j) * TB + t0 + lane] = fmax(v, 0.0);
  }
}

// f64 conv 64->64, K=9, SAME. out = relu(conv(in)+bias [+ skip])
template <bool SKIP>
__global__ __launch_bounds__(256) void conv64_f64_kernel(
    const double* __restrict__ in, const double* __restrict__ wT,
    const float* __restrict__ bias, const double* __restrict__ skip,
    double* __restrict__ out) {
  __shared__ double xs[64 * 72];
  int b = blockIdx.y;
  int t0 = blockIdx.x * 64;
  int tid = threadIdx.x;
  for (int i = tid; i < 64 * 72; i += 256) {
    int cin = i / 72, tt = i % 72;
    int t = t0 - 4 + tt;
    xs[i] = (t >= 0 && t < TB) ? in[(b * 64 + cin) * TB + t] : 0.0;
  }
  __syncthreads();
  int wave = __builtin_amdgcn_readfirstlane(tid >> 6);
  int lane = tid & 63;
  int cbase = wave * 16;
  double acc[16];
#pragma unroll
  for (int j = 0; j < 16; ++j) acc[j] = (double)bias[cbase + j];
  for (int cin = 0; cin < 64; ++cin) {
#pragma unroll
    for (int k = 0; k < 9; ++k) {
      double xv = xs[cin * 72 + lane + k];
      const double* wp = wT + (k * 64 + cin) * 64 + cbase;
#pragma unroll
      for (int j = 0; j < 16; ++j) acc[j] = fma(xv, wp[j], acc[j]);
    }
  }
  int t = t0 + lane;
#pragma unroll
  for (int j = 0; j < 16; ++j) {
    double v = acc[j];
    if constexpr (SKIP) v += skip[(b * 64 + cbase + j) * TB + t];
    out[(b * 64 + cbase + j) * TB + t] = fmax(v, 0.0);
  }
}

// f32 conv 32->32 (decoder), K=9, SAME
template <bool SKIP>
__global__ __launch_bounds__(256) void conv32_f32_kernel(
    const float* __restrict__ in, const float* __restrict__ wT,
    const float* __restrict__ bias, const float* __restrict__ skip,
    float* __restrict__ out) {
  constexpr int XW = 136;
  __shared__ float xs[32 * XW];
  int b = blockIdx.y;
  int t0 = blockIdx.x * 128;
  int tid = threadIdx.x;
  for (int i = tid; i < 32 * XW; i += 256) {
    int cin = i / XW, tt = i % XW;
    int t = t0 - 4 + tt;
    xs[i] = (t >= 0 && t < TB) ? in[(b * 32 + cin) * TB + t] : 0.f;
  }
  __syncthreads();
  int wave = __builtin_amdgcn_readfirstlane(tid >> 6);
  int lane = tid & 63;
  int cbase = (wave & 1) * 16;
  int ttl = (wave >> 1) * 64 + lane;
  float acc[16];
#pragma unroll
  for (int j = 0; j < 16; ++j) acc[j] = bias[cbase + j];
  for (int cin = 0; cin < 32; ++cin) {
#pragma unroll
    for (int k = 0; k < 9; ++k) {
      float xv = xs[cin * XW + ttl + k];
      const float* wp = wT + (k * 32 + cin) * 32 + cbase;
#pragma unroll
      for (int j = 0; j < 16; ++j) acc[j] = fmaf(xv, wp[j], acc[j]);
    }
  }
  int t = t0 + ttl;
#pragma unroll
  for (int j = 0; j < 16; ++j) {
    float v = acc[j];
    if constexpr (SKIP) v += skip[(b * 32 + cbase + j) * TB + t];
    out[(b * 32 + cbase + j) * TB + t] = fmaxf(v, 0.f);
  }
}

// code_assign (f64 distances/argmin, f32 q): h f64 (BC,64,512) channels
// [coff,coff+32) vs means (32,M). Online softmax; writes q f32, idx f32.
template <int M>
__global__ __launch_bounds__(256) void code_assign_kernel(
    const double* __restrict__ h, int coff, const float* __restrict__ means,
    float* __restrict__ q, float* __restrict__ idx_out) {
  __shared__ double ms[32 * M];
  __shared__ float msf[32 * M];
  __shared__ double msq[M];
  int b = blockIdx.y;
  int tid = threadIdx.x;
  int t = blockIdx.x * 256 + tid;
  for (int i = tid; i < 32 * M; i += 256) {
    float v = means[i];
    ms[i] = (double)v;
    msf[i] = v;
  }
  __syncthreads();
  if (tid < M) {
    double s = 0.0;
#pragma unroll
    for (int c = 0; c < 32; ++c) s = fma(ms[c * M + tid], ms[c * M + tid], s);
    msq[tid] = s;
  }
  __syncthreads();
  double xv[32];
  double sx = 0.0;
#pragma unroll
  for (int c = 0; c < 32; ++c) {
    xv[c] = h[(b * 64 + coff + c) * TB + t];
    sx = fma(xv[c], xv[c], sx);
  }
  double dmin = 1e300;
  int imin = 0;
  float ssum = 0.f;
  float qv[32];
#pragma unroll
  for (int c = 0; c < 32; ++c) qv[c] = 0.f;
  for (int m = 0; m < M; ++m) {
    double dot = 0.0;
#pragma unroll
    for (int c = 0; c < 32; ++c) dot = fma(xv[c], ms[c * M + m], dot);
    double d = sx - 2.0 * dot + msq[m];
    float p;
    if (d < dmin) {
      float f = expf((float)(d - dmin));  // rescale old weights to new min
      ssum *= f;
#pragma unroll
      for (int c = 0; c < 32; ++c) qv[c] *= f;
      dmin = d;
      imin = m;
      p = 1.f;
    } else {
      p = expf((float)(dmin - d));
    }
    ssum += p;
#pragma unroll
    for (int c = 0; c < 32; ++c) qv[c] = fmaf(p, msf[c * M + m], qv[c]);
  }
  float inv = 1.f / ssum;
#pragma unroll
  for (int c = 0; c < 32; ++c) q[(b * 32 + c) * TB + t] = qv[c] * inv;
  idx_out[b * TB + t] = (float)imin;
}

// FC + tanh: out[m][n] = tanh(sum_k z[m][k]*w[n][k] + b[n]); N=512, K=16384
__global__ __launch_bounds__(256) void fc_tanh_kernel(
    const float* __restrict__ zs, const float* __restrict__ zn,
    const float* __restrict__ w, const float* __restrict__ bias,
    float* __restrict__ outbase) {
  constexpr int BK = 16;
  __shared__ float As[BK][32];
  __shared__ float Bs[BK][32];
  const float* z = blockIdx.z ? zn : zs;
  float* out = outbase + (size_t)blockIdx.z * 524288;
  int m0 = blockIdx.y * 32;
  int n0 = blockIdx.x * 32;
  int tid = threadIdx.x;
  int mg = tid >> 4;
  int ng = tid & 15;
  float acc[2][2] = {};
  for (int k0 = 0; k0 < 16384; k0 += BK) {
    int r = (tid & 127) >> 2;
    int kq = (tid & 3) * 4;
    if (tid < 128) {
      float4 v = *(const float4*)&z[(size_t)(m0 + r) * 16384 + k0 + kq];
      As[kq + 0][r] = v.x; As[kq + 1][r] = v.y;
      As[kq + 2][r] = v.z; As[kq + 3][r] = v.w;
    } else {
      float4 v = *(const float4*)&w[(size_t)(n0 + r) * 16384 + k0 + kq];
      Bs[kq + 0][r] = v.x; Bs[kq + 1][r] = v.y;
      Bs[kq + 2][r] = v.z; Bs[kq + 3][r] = v.w;
    }
    __syncthreads();
#pragma unroll
    for (int kk = 0; kk < BK; ++kk) {
      float a0 = As[kk][2 * mg], a1 = As[kk][2 * mg + 1];
      float b0 = Bs[kk][2 * ng], b1 = Bs[kk][2 * ng + 1];
      acc[0][0] = fmaf(a0, b0, acc[0][0]);
      acc[0][1] = fmaf(a0, b1, acc[0][1]);
      acc[1][0] = fmaf(a1, b0, acc[1][0]);
      acc[1][1] = fmaf(a1, b1, acc[1][1]);
    }
    __syncthreads();
  }
#pragma unroll
  for (int mi = 0; mi < 2; ++mi)
#pragma unroll
    for (int ni = 0; ni < 2; ++ni) {
      int n = n0 + 2 * ng + ni;
      out[(size_t)(m0 + 2 * mg + mi) * 512 + n] = tanhf(acc[mi][ni] + bias[n]);
    }
}

extern "C" void kernel_launch(void* const* d_in, const int* in_sizes, int n_in,
                              void* d_out, int out_size, void* d_ws,
                              size_t ws_size, hipStream_t stream) {
  const float* x = (const float*)d_in[0];
  const float* enc0_w1 = (const float*)d_in[1];
  const float* enc0_b1 = (const float*)d_in[2];
  const float* enc0_w2 = (const float*)d_in[3];
  const float* enc0_b2 = (const float*)d_in[4];
  const float* enc0_ws = (const float*)d_in[5];
  const float* enc0_bs = (const float*)d_in[6];
  const float* enc_w = (const float*)d_in[7];
  const float* enc_b = (const float*)d_in[8];
  const float* dec_w = (const float*)d_in[9];
  const float* dec_b = (const float*)d_in[10];
  const float* fc1_w = (const float*)d_in[11];
  const float* fc1_b = (const float*)d_in[12];
  const float* means_s = (const float*)d_in[13];
  const float* means_n = (const float*)d_in[14];

  // workspace: [f64: wT0d(36864) wTed(221184) E0d(BC*32768) E1d(BC*32768)]
  //            [f32: wTdf(55296) D0 D1 qs qn (BC*16384 each)]
  const size_t FIXED = 2285568;       // bytes
  const size_t PER_BC = 786432;       // bytes per batch row
  int BC = 32;
  for (int c = 1024; c >= 32; c >>= 1) {
    if (FIXED + (size_t)c * PER_BC <= ws_size) { BC = c; break; }
  }

  double* wT0d = (double*)d_ws;
  double* wTed = wT0d + 36864;
  double* E0d = wTed + 221184;
  double* E1d = E0d + (size_t)BC * 32768;
  float* wTdf = (float*)(E1d + (size_t)BC * 32768);
  float* D0f = wTdf + 55296;
  float* D1f = D0f + (size_t)BC * 16384;
  float* qsf = D1f + (size_t)BC * 16384;
  float* qnf = qsf + (size_t)BC * 16384;
  float* out = (float*)d_out;

  transpose_w_f64_kernel<<<dim3(144), 256, 0, stream>>>(enc0_w2, wT0d, 64, 1);
  transpose_w_f64_kernel<<<dim3(864), 256, 0, stream>>>(enc_w, wTed, 64, 6);
  transpose_w_f32_kernel<<<dim3(216), 256, 0, stream>>>(dec_w, wTdf, 32, 6);

  for (int c0 = 0; c0 < BATCH; c0 += BC) {
    const float* xb = x + (size_t)c0 * TB;

    // encoder (f64)
    enc0_f64_kernel<<<dim3(8, BC), 256, 0, stream>>>(
        xb, enc0_w1, enc0_b1, wT0d, enc0_b2, enc0_ws, enc0_bs, E0d);
    for (int i = 0; i < 3; ++i) {
      conv64_f64_kernel<false><<<dim3(8, BC), 256, 0, stream>>>(
          E0d, wTed + (2 * i) * 36864, enc_b + (2 * i) * 64, nullptr, E1d);
      conv64_f64_kernel<true><<<dim3(8, BC), 256, 0, stream>>>(
          E1d, wTed + (2 * i + 1) * 36864, enc_b + (2 * i + 1) * 64, E0d, E0d);
    }

    // vector-quantize (f64 argmin; writes idx outputs directly)
    code_assign_kernel<64><<<dim3(2, BC), 256, 0, stream>>>(
        E0d, 0, means_s, qsf, out + 2 * 524288 + (size_t)c0 * TB);
    code_assign_kernel<32><<<dim3(2, BC), 256, 0, stream>>>(
        E0d, 32, means_n, qnf, out + 3 * 524288 + (size_t)c0 * TB);

    // decoder s: qsf -> D1f
    {
      const float* zin = qsf;
      for (int i = 0; i < 3; ++i) {
        conv32_f32_kernel<false><<<dim3(4, BC), 256, 0, stream>>>(
            zin, wTdf + (2 * i) * 9216, dec_b + (2 * i) * 32, nullptr, D0f);
        conv32_f32_kernel<true><<<dim3(4, BC), 256, 0, stream>>>(
            D0f, wTdf + (2 * i + 1) * 9216, dec_b + (2 * i + 1) * 32, zin, D1f);
        zin = D1f;
      }
    }
    // decoder n: qnf -> qsf (dead after decoder s)
    {
      float* Z = qsf;
      const float* zin = qnf;
      for (int i = 0; i < 3; ++i) {
        conv32_f32_kernel<false><<<dim3(4, BC), 256, 0, stream>>>(
            zin, wTdf + (2 * i) * 9216, dec_b + (2 * i) * 32, nullptr, D0f);
        conv32_f32_kernel<true><<<dim3(4, BC), 256, 0, stream>>>(
            D0f, wTdf + (2 * i + 1) * 9216, dec_b + (2 * i + 1) * 32, zin, Z);
        zin = Z;
      }
    }

    // FC + tanh for both streams
    fc_tanh_kernel<<<dim3(16, BC / 32, 2), 256, 0, stream>>>(
        D1f, qsf, fc1_w, fc1_b, out + (size_t)c0 * TB);
  }
}